// Round 12
// baseline (32.284 us; speedup 1.0000x reference)
//
#include <hip/hip_runtime.h>
#include <hip/hip_bf16.h>
#include <cstddef>

#define D_IN 512
#define BLOCK 256
#define RPW 16     // rows per wave (8 passes x 2 rows)
#define RPB 64     // rows per block = 4 waves x 16 rows

typedef float f4 __attribute__((ext_vector_type(4)));

// ---------------------------------------------------------------------------
// Gate helpers (M-build only). Template params keep all state[] indices
// compile-time (registers, never scratch — R4 lesson). Wire q = bit (3-q).
// ---------------------------------------------------------------------------
template<int BIT>
__device__ __forceinline__ void applyG(float* sr, float* si,
    float u00r, float u00i, float u01r, float u01i,
    float u10r, float u10i, float u11r, float u11i)
{
#pragma unroll
    for (int m = 0; m < 8; ++m) {
        const int lo = m & (BIT - 1);
        const int i0 = ((m ^ lo) << 1) | lo;
        const int i1 = i0 | BIT;
        float a0r = sr[i0], a0i = si[i0];
        float a1r = sr[i1], a1i = si[i1];
        float n0r = u00r * a0r - u00i * a0i + u01r * a1r - u01i * a1i;
        float n0i = u00r * a0i + u00i * a0r + u01r * a1i + u01i * a1r;
        float n1r = u10r * a0r - u10i * a0i + u11r * a1r - u11i * a1i;
        float n1i = u10r * a0i + u10i * a0r + u11r * a1i + u11i * a1r;
        sr[i0] = n0r; si[i0] = n0i;
        sr[i1] = n1r; si[i1] = n1i;
    }
}

template<int CB, int TB>
__device__ __forceinline__ void applyCNOT(float* sr, float* si)
{
    constexpr int FREE = 15 & ~CB & ~TB;
    constexpr int LO = FREE & (-FREE);
    constexpr int HI = FREE ^ LO;
#pragma unroll
    for (int m = 0; m < 4; ++m) {
        const int idx = CB | ((m & 1) ? LO : 0) | ((m & 2) ? HI : 0);
        const int j = idx | TB;
        float tr = sr[idx]; sr[idx] = sr[j]; sr[j] = tr;
        float ti = si[idx]; si[idx] = si[j]; si[j] = ti;
    }
}

// ---------------------------------------------------------------------------
// M-build (runs in gemm's block 0, wave 0): M is 16x16 real symmetric with
// out = r^T M r, r[idx] = prod_q (bit_q(idx) ? sin(a_q/2) : cos(a_q/2)).
// amp_embedded = (-i)^pop(idx) r[idx]; final = U amp = V r,
// V[:,j] = (-i)^pop(j) U e_j; M = sum_k (1-pop(k)/2)(VR_k VR_k^T + VI_k VI_k^T).
// M is consumed only by the NEXT kernel -> kernel boundary is the sync.
// ---------------------------------------------------------------------------
__device__ void build_M(const float* __restrict__ w, float* __restrict__ M,
                        float VR[16][16], float VI[16][16], int lane)
{
    float sr[16], si[16];
#pragma unroll
    for (int i = 0; i < 16; ++i) {
        sr[i] = (i == lane) ? 1.f : 0.f;   // basis e_lane (lanes>=16 all zero)
        si[i] = 0.f;
    }

#define ROTG(g, q)                                                          \
    {                                                                       \
        float phi = w[(g) * 3 + 0], th = w[(g) * 3 + 1],                    \
              om  = w[(g) * 3 + 2];                                         \
        float sn, cs;  sincosf(th * 0.5f, &sn, &cs);                        \
        float sa, ca;  sincosf((phi + om) * 0.5f, &sa, &ca);                \
        float sd, cd;  sincosf((phi - om) * 0.5f, &sd, &cd);                \
        applyG<(1 << (3 - (q)))>(sr, si,  cs * ca, -cs * sa,                \
                                 -sn * cd, -sn * sd,                        \
                                  sn * cd, -sn * sd,                        \
                                  cs * ca,  cs * sa);                       \
    }
    // Layer 0: Rot wires 0..3, CNOT ring range 1
    ROTG(0, 0) ROTG(1, 1) ROTG(2, 2) ROTG(3, 3)
    applyCNOT<8, 4>(sr, si);
    applyCNOT<4, 2>(sr, si);
    applyCNOT<2, 1>(sr, si);
    applyCNOT<1, 8>(sr, si);
    // Layer 1: Rot, CNOT ring range 2
    ROTG(4, 0) ROTG(5, 1) ROTG(6, 2) ROTG(7, 3)
    applyCNOT<8, 2>(sr, si);
    applyCNOT<4, 1>(sr, si);
    applyCNOT<2, 8>(sr, si);
    applyCNOT<1, 4>(sr, si);
#undef ROTG

    if (lane < 16) {
        const int pm = __popc(lane) & 3;   // V[:,j] = (-i)^pop(j) U[:,j]
#pragma unroll
        for (int k = 0; k < 16; ++k) {
            float re = sr[k], im = si[k];
            float vr = (pm == 0) ? re : (pm == 1) ? im
                     : (pm == 2) ? -re : -im;
            float vi = (pm == 0) ? im : (pm == 1) ? -re
                     : (pm == 2) ? -im : re;
            VR[k][lane] = vr;  VI[k][lane] = vi;
        }
    }
    // single wave: in-wave LDS write->read ordering handled by compiler waits
#pragma unroll
    for (int q = 0; q < 4; ++q) {
        const int e = lane + q * 64;
        const int j = e >> 4, b = e & 15;
        float acc = 0.f;
#pragma unroll
        for (int k = 0; k < 16; ++k) {
            const float wk = 1.0f - 0.5f * (float)__popc(k);
            acc += wk * (VR[k][j] * VR[k][b] + VI[k][j] * VI[k][b]);
        }
        M[e] = acc;
    }
}

// ---------------------------------------------------------------------------
// Kernel A (GEMM) — R10's best-measured core (29.92us), single change:
// x loads are NONTEMPORAL. x is 128MB read exactly once (4x aggregate L2);
// normal loads allocate guaranteed-dead L2 lines. nt streams past, removing
// allocation/eviction overhead from the TCC pipeline. Strict A/B vs R10.
// Lane roles: sub = k-chunk of 32 (coalesced 512B segments), half = row of
// pair. Weights in 16 f4 regs. 6-shuffle reduce. Block 0 wave 0 builds M.
// ---------------------------------------------------------------------------
__global__ __launch_bounds__(BLOCK) void qhead_gemm(
    const float* __restrict__ x,
    const float* __restrict__ fc_w,
    const float* __restrict__ w,
    float* __restrict__ M,
    float* __restrict__ dots, int B)
{
    __shared__ float VR[16][16], VI[16][16];

    const int t    = threadIdx.x;
    const int lane = t & 63;
    const int wv   = t >> 6;
    const int sub  = lane & 31;
    const int half = lane >> 5;
    const int row0 = blockIdx.x * RPB + wv * RPW;

    if (blockIdx.x == 0 && wv == 0)
        build_M(w, M, VR, VI, lane);

    // weights: 16 f4 regs per lane (row j, chunk it*32+sub)
    const f4* w4 = (const f4*)fc_w;
    f4 wreg[4][4];
#pragma unroll
    for (int jj = 0; jj < 4; ++jj)
#pragma unroll
        for (int it = 0; it < 4; ++it)
            wreg[jj][it] = w4[jj * 128 + it * 32 + sub];

    const f4* x4 = (const f4*)x;

#pragma unroll
    for (int p = 0; p < RPW / 2; ++p) {
        int rp = row0 + p * 2 + half;
        if (rp >= B) rp = B - 1;
        const f4* xr = x4 + (size_t)rp * 128 + sub;

        f4 xv[4];
#pragma unroll
        for (int c = 0; c < 4; ++c)
            xv[c] = __builtin_nontemporal_load(xr + c * 32);

        float s0 = 0.f, s1 = 0.f, s2 = 0.f, s3 = 0.f;
#pragma unroll
        for (int c = 0; c < 4; ++c) {
            f4 v = xv[c];
            s0 += v[0]*wreg[0][c][0] + v[1]*wreg[0][c][1]
                + v[2]*wreg[0][c][2] + v[3]*wreg[0][c][3];
            s1 += v[0]*wreg[1][c][0] + v[1]*wreg[1][c][1]
                + v[2]*wreg[1][c][2] + v[3]*wreg[1][c][3];
            s2 += v[0]*wreg[2][c][0] + v[1]*wreg[2][c][1]
                + v[2]*wreg[2][c][2] + v[3]*wreg[2][c][3];
            s3 += v[0]*wreg[3][c][0] + v[1]*wreg[3][c][1]
                + v[2]*wreg[3][c][2] + v[3]*wreg[3][c][3];
        }

        // 6-shuffle reduce within the 32-lane group:
        float a01 = (sub & 1) ? s1 : s0;
        float b01 = (sub & 1) ? s0 : s1;
        a01 += __shfl_xor(b01, 1);
        float a23 = (sub & 1) ? s3 : s2;
        float b23 = (sub & 1) ? s2 : s3;
        a23 += __shfl_xor(b23, 1);
        float v = (sub & 2) ? a23 : a01;
        float u = (sub & 2) ? a01 : a23;
        v += __shfl_xor(u, 2);
        v += __shfl_xor(v, 4);
        v += __shfl_xor(v, 8);
        v += __shfl_xor(v, 16);

        if (sub < 4) dots[(size_t)rp * 4 + sub] = v;
    }
}

// ---------------------------------------------------------------------------
// Kernel B (sim): row-per-thread. 1 coalesced f4 load of raw dots (L2-hot),
// bias+tanh, 4 sincos, out = r^T M r. M address is uniform -> s_load, L1-hot.
// ---------------------------------------------------------------------------
__global__ __launch_bounds__(256) void qhead_sim(
    const float* __restrict__ dots,
    const float* __restrict__ fc_b,
    const float* __restrict__ Mg,
    float* __restrict__ out, int B)
{
    const int r = blockIdx.x * 256 + threadIdx.x;
    if (r >= B) return;

    f4 d = ((const f4*)dots)[r];
    float c0, c1, c2, c3, s0, s1, s2, s3;
    sincosf(tanhf(d[0] + fc_b[0]) * 0.5f, &s0, &c0);
    sincosf(tanhf(d[1] + fc_b[1]) * 0.5f, &s1, &c1);
    sincosf(tanhf(d[2] + fc_b[2]) * 0.5f, &s2, &c2);
    sincosf(tanhf(d[3] + fc_b[3]) * 0.5f, &s3, &c3);

    // r[idx]: bit3 = wire0 ... bit0 = wire3
    float rA[4] = { c0*c1, c0*s1, s0*c1, s0*s1 };
    float rB[4] = { c2*c3, c2*s3, s2*c3, s2*s3 };
    float rv[16];
#pragma unroll
    for (int uu = 0; uu < 4; ++uu)
#pragma unroll
        for (int vv = 0; vv < 4; ++vv)
            rv[uu * 4 + vv] = rA[uu] * rB[vv];

    const f4* M4 = (const f4*)Mg;
    float res = 0.f;
#pragma unroll
    for (int a = 0; a < 16; ++a) {
        float ta = 0.f;
#pragma unroll
        for (int bq = 0; bq < 4; ++bq) {
            f4 m = M4[a * 4 + bq];
            ta += m[0] * rv[bq * 4 + 0] + m[1] * rv[bq * 4 + 1]
                + m[2] * rv[bq * 4 + 2] + m[3] * rv[bq * 4 + 3];
        }
        res += ta * rv[a];
    }
    out[r] = res;
}

extern "C" void kernel_launch(void* const* d_in, const int* in_sizes, int n_in,
                              void* d_out, int out_size, void* d_ws, size_t ws_size,
                              hipStream_t stream)
{
    const float* x    = (const float*)d_in[0];
    const float* fc_w = (const float*)d_in[1];
    const float* fc_b = (const float*)d_in[2];
    const float* w    = (const float*)d_in[3];
    float* out  = (float*)d_out;
    float* M    = (float*)d_ws;                  // 256 floats
    float* dots = (float*)d_ws + 256;            // 65536*4 floats

    const int B = in_sizes[0] / D_IN;

    qhead_gemm<<<(B + RPB - 1) / RPB, BLOCK, 0, stream>>>(
        x, fc_w, w, M, dots, B);
    qhead_sim<<<(B + 255) / 256, 256, 0, stream>>>(dots, fc_b, M, out, B);
}

// Round 13
// 29.947 us; speedup vs baseline: 1.0781x; 1.0781x over previous
//
#include <hip/hip_runtime.h>
#include <hip/hip_bf16.h>
#include <cstddef>

#define D_IN 512
#define BLOCK 256
#define RPW 16     // rows per wave (8 passes x 2 rows)
#define RPB 64     // rows per block = 4 waves x 16 rows

typedef float f4 __attribute__((ext_vector_type(4)));

// ---------------------------------------------------------------------------
// Gate helpers (M-build only). Template params keep all state[] indices
// compile-time (registers, never scratch — R4 lesson). Wire q = bit (3-q).
// ---------------------------------------------------------------------------
template<int BIT>
__device__ __forceinline__ void applyG(float* sr, float* si,
    float u00r, float u00i, float u01r, float u01i,
    float u10r, float u10i, float u11r, float u11i)
{
#pragma unroll
    for (int m = 0; m < 8; ++m) {
        const int lo = m & (BIT - 1);
        const int i0 = ((m ^ lo) << 1) | lo;
        const int i1 = i0 | BIT;
        float a0r = sr[i0], a0i = si[i0];
        float a1r = sr[i1], a1i = si[i1];
        float n0r = u00r * a0r - u00i * a0i + u01r * a1r - u01i * a1i;
        float n0i = u00r * a0i + u00i * a0r + u01r * a1i + u01i * a1r;
        float n1r = u10r * a0r - u10i * a0i + u11r * a1r - u11i * a1i;
        float n1i = u10r * a0i + u10i * a0r + u11r * a1i + u11i * a1r;
        sr[i0] = n0r; si[i0] = n0i;
        sr[i1] = n1r; si[i1] = n1i;
    }
}

template<int CB, int TB>
__device__ __forceinline__ void applyCNOT(float* sr, float* si)
{
    constexpr int FREE = 15 & ~CB & ~TB;
    constexpr int LO = FREE & (-FREE);
    constexpr int HI = FREE ^ LO;
#pragma unroll
    for (int m = 0; m < 4; ++m) {
        const int idx = CB | ((m & 1) ? LO : 0) | ((m & 2) ? HI : 0);
        const int j = idx | TB;
        float tr = sr[idx]; sr[idx] = sr[j]; sr[j] = tr;
        float ti = si[idx]; si[idx] = si[j]; si[j] = ti;
    }
}

// ---------------------------------------------------------------------------
// M-build (runs in gemm's block 0, wave 0): M is 16x16 real symmetric with
// out = r^T M r, r[idx] = prod_q (bit_q(idx) ? sin(a_q/2) : cos(a_q/2)).
// amp_embedded = (-i)^pop(idx) r[idx]; final = U amp = V r,
// V[:,j] = (-i)^pop(j) U e_j; M = sum_k (1-pop(k)/2)(VR_k VR_k^T + VI_k VI_k^T).
// M is consumed only by the NEXT kernel -> kernel boundary is the sync.
// ---------------------------------------------------------------------------
__device__ void build_M(const float* __restrict__ w, float* __restrict__ M,
                        float VR[16][16], float VI[16][16], int lane)
{
    float sr[16], si[16];
#pragma unroll
    for (int i = 0; i < 16; ++i) {
        sr[i] = (i == lane) ? 1.f : 0.f;   // basis e_lane (lanes>=16 all zero)
        si[i] = 0.f;
    }

#define ROTG(g, q)                                                          \
    {                                                                       \
        float phi = w[(g) * 3 + 0], th = w[(g) * 3 + 1],                    \
              om  = w[(g) * 3 + 2];                                         \
        float sn, cs;  sincosf(th * 0.5f, &sn, &cs);                        \
        float sa, ca;  sincosf((phi + om) * 0.5f, &sa, &ca);                \
        float sd, cd;  sincosf((phi - om) * 0.5f, &sd, &cd);                \
        applyG<(1 << (3 - (q)))>(sr, si,  cs * ca, -cs * sa,                \
                                 -sn * cd, -sn * sd,                        \
                                  sn * cd, -sn * sd,                        \
                                  cs * ca,  cs * sa);                       \
    }
    // Layer 0: Rot wires 0..3, CNOT ring range 1
    ROTG(0, 0) ROTG(1, 1) ROTG(2, 2) ROTG(3, 3)
    applyCNOT<8, 4>(sr, si);
    applyCNOT<4, 2>(sr, si);
    applyCNOT<2, 1>(sr, si);
    applyCNOT<1, 8>(sr, si);
    // Layer 1: Rot, CNOT ring range 2
    ROTG(4, 0) ROTG(5, 1) ROTG(6, 2) ROTG(7, 3)
    applyCNOT<8, 2>(sr, si);
    applyCNOT<4, 1>(sr, si);
    applyCNOT<2, 8>(sr, si);
    applyCNOT<1, 4>(sr, si);
#undef ROTG

    if (lane < 16) {
        const int pm = __popc(lane) & 3;   // V[:,j] = (-i)^pop(j) U[:,j]
#pragma unroll
        for (int k = 0; k < 16; ++k) {
            float re = sr[k], im = si[k];
            float vr = (pm == 0) ? re : (pm == 1) ? im
                     : (pm == 2) ? -re : -im;
            float vi = (pm == 0) ? im : (pm == 1) ? -re
                     : (pm == 2) ? -im : re;
            VR[k][lane] = vr;  VI[k][lane] = vi;
        }
    }
    // single wave: in-wave LDS write->read ordering handled by compiler waits
#pragma unroll
    for (int q = 0; q < 4; ++q) {
        const int e = lane + q * 64;
        const int j = e >> 4, b = e & 15;
        float acc = 0.f;
#pragma unroll
        for (int k = 0; k < 16; ++k) {
            const float wk = 1.0f - 0.5f * (float)__popc(k);
            acc += wk * (VR[k][j] * VR[k][b] + VI[k][j] * VI[k][b]);
        }
        M[e] = acc;
    }
}

// ---------------------------------------------------------------------------
// Kernel A (GEMM) — best-measured core (R10, 29.92us), restored after the
// NT-load A/B regressed (R12: 32.3us — nt read hints hurt on gfx950).
// Lane roles: sub = k-chunk of 32 (coalesced 512B segments), half = row of
// pair. Weights in 16 f4 regs; plain loads, compiler-scheduled pipelining
// (no launch_bounds cap — R8 showed capping VGPR kills it). 6-shuffle
// reduce. Block 0 wave 0 also builds M into ws.
// ---------------------------------------------------------------------------
__global__ __launch_bounds__(BLOCK) void qhead_gemm(
    const float* __restrict__ x,
    const float* __restrict__ fc_w,
    const float* __restrict__ w,
    float* __restrict__ M,
    float* __restrict__ dots, int B)
{
    __shared__ float VR[16][16], VI[16][16];

    const int t    = threadIdx.x;
    const int lane = t & 63;
    const int wv   = t >> 6;
    const int sub  = lane & 31;
    const int half = lane >> 5;
    const int row0 = blockIdx.x * RPB + wv * RPW;

    if (blockIdx.x == 0 && wv == 0)
        build_M(w, M, VR, VI, lane);

    // weights: 16 f4 regs per lane (row j, chunk it*32+sub)
    const f4* w4 = (const f4*)fc_w;
    f4 wreg[4][4];
#pragma unroll
    for (int jj = 0; jj < 4; ++jj)
#pragma unroll
        for (int it = 0; it < 4; ++it)
            wreg[jj][it] = w4[jj * 128 + it * 32 + sub];

    const f4* x4 = (const f4*)x;

#pragma unroll
    for (int p = 0; p < RPW / 2; ++p) {
        int rp = row0 + p * 2 + half;
        if (rp >= B) rp = B - 1;
        const f4* xr = x4 + (size_t)rp * 128 + sub;

        f4 xv[4];
#pragma unroll
        for (int c = 0; c < 4; ++c) xv[c] = xr[c * 32];

        float s0 = 0.f, s1 = 0.f, s2 = 0.f, s3 = 0.f;
#pragma unroll
        for (int c = 0; c < 4; ++c) {
            f4 v = xv[c];
            s0 += v[0]*wreg[0][c][0] + v[1]*wreg[0][c][1]
                + v[2]*wreg[0][c][2] + v[3]*wreg[0][c][3];
            s1 += v[0]*wreg[1][c][0] + v[1]*wreg[1][c][1]
                + v[2]*wreg[1][c][2] + v[3]*wreg[1][c][3];
            s2 += v[0]*wreg[2][c][0] + v[1]*wreg[2][c][1]
                + v[2]*wreg[2][c][2] + v[3]*wreg[2][c][3];
            s3 += v[0]*wreg[3][c][0] + v[1]*wreg[3][c][1]
                + v[2]*wreg[3][c][2] + v[3]*wreg[3][c][3];
        }

        // 6-shuffle reduce within the 32-lane group:
        float a01 = (sub & 1) ? s1 : s0;
        float b01 = (sub & 1) ? s0 : s1;
        a01 += __shfl_xor(b01, 1);
        float a23 = (sub & 1) ? s3 : s2;
        float b23 = (sub & 1) ? s2 : s3;
        a23 += __shfl_xor(b23, 1);
        float v = (sub & 2) ? a23 : a01;
        float u = (sub & 2) ? a01 : a23;
        v += __shfl_xor(u, 2);
        v += __shfl_xor(v, 4);
        v += __shfl_xor(v, 8);
        v += __shfl_xor(v, 16);

        if (sub < 4) dots[(size_t)rp * 4 + sub] = v;
    }
}

// ---------------------------------------------------------------------------
// Kernel B (sim): row-per-thread. 1 coalesced f4 load of raw dots (L2-hot),
// bias+tanh, 4 sincos, out = r^T M r. M address is uniform -> s_load, L1-hot.
// ---------------------------------------------------------------------------
__global__ __launch_bounds__(256) void qhead_sim(
    const float* __restrict__ dots,
    const float* __restrict__ fc_b,
    const float* __restrict__ Mg,
    float* __restrict__ out, int B)
{
    const int r = blockIdx.x * 256 + threadIdx.x;
    if (r >= B) return;

    f4 d = ((const f4*)dots)[r];
    float c0, c1, c2, c3, s0, s1, s2, s3;
    sincosf(tanhf(d[0] + fc_b[0]) * 0.5f, &s0, &c0);
    sincosf(tanhf(d[1] + fc_b[1]) * 0.5f, &s1, &c1);
    sincosf(tanhf(d[2] + fc_b[2]) * 0.5f, &s2, &c2);
    sincosf(tanhf(d[3] + fc_b[3]) * 0.5f, &s3, &c3);

    // r[idx]: bit3 = wire0 ... bit0 = wire3
    float rA[4] = { c0*c1, c0*s1, s0*c1, s0*s1 };
    float rB[4] = { c2*c3, c2*s3, s2*c3, s2*s3 };
    float rv[16];
#pragma unroll
    for (int uu = 0; uu < 4; ++uu)
#pragma unroll
        for (int vv = 0; vv < 4; ++vv)
            rv[uu * 4 + vv] = rA[uu] * rB[vv];

    const f4* M4 = (const f4*)Mg;
    float res = 0.f;
#pragma unroll
    for (int a = 0; a < 16; ++a) {
        float ta = 0.f;
#pragma unroll
        for (int bq = 0; bq < 4; ++bq) {
            f4 m = M4[a * 4 + bq];
            ta += m[0] * rv[bq * 4 + 0] + m[1] * rv[bq * 4 + 1]
                + m[2] * rv[bq * 4 + 2] + m[3] * rv[bq * 4 + 3];
        }
        res += ta * rv[a];
    }
    out[r] = res;
}

extern "C" void kernel_launch(void* const* d_in, const int* in_sizes, int n_in,
                              void* d_out, int out_size, void* d_ws, size_t ws_size,
                              hipStream_t stream)
{
    const float* x    = (const float*)d_in[0];
    const float* fc_w = (const float*)d_in[1];
    const float* fc_b = (const float*)d_in[2];
    const float* w    = (const float*)d_in[3];
    float* out  = (float*)d_out;
    float* M    = (float*)d_ws;                  // 256 floats
    float* dots = (float*)d_ws + 256;            // 65536*4 floats

    const int B = in_sizes[0] / D_IN;

    qhead_gemm<<<(B + RPB - 1) / RPB, BLOCK, 0, stream>>>(
        x, fc_w, w, M, dots, B);
    qhead_sim<<<(B + 255) / 256, 256, 0, stream>>>(dots, fc_b, M, out, B);
}